// Round 5
// baseline (86.220 us; speedup 1.0000x reference)
//
#include <hip/hip_runtime.h>

typedef _Float16 f16x8 __attribute__((ext_vector_type(8)));
typedef __fp16   h16x2 __attribute__((ext_vector_type(2)));
typedef float    f32x4 __attribute__((ext_vector_type(4)));

#define NB   8
#define CIN  256
#define CC   512
#define SS   1024
#define NH   8
#define DH   64

static __device__ __forceinline__ ushort f2h(float f) {
  union { _Float16 h; ushort u; } cv;
  cv.h = (_Float16)f;
  return cv.u;
}

// ---------------------------------------------------------------------------
// Kernel 1: weight-norm  w[c,i] = g[c] * v[c,i] / ||v[c,:]||   -> f16
// ---------------------------------------------------------------------------
__global__ __launch_bounds__(256)
void wnorm_kernel(const float* __restrict__ vq, const float* __restrict__ gq,
                  const float* __restrict__ vk, const float* __restrict__ gk,
                  const float* __restrict__ vv, const float* __restrict__ gv,
                  ushort* __restrict__ w_all) {
  const int c   = blockIdx.x;
  const int mat = blockIdx.y;
  const int t   = threadIdx.x;
  const float* v = (mat == 0) ? vq : (mat == 1) ? vk : vv;
  const float* g = (mat == 0) ? gq : (mat == 1) ? gk : gv;

  float val = v[c * CIN + t];
  float s = val * val;
  #pragma unroll
  for (int off = 32; off; off >>= 1) s += __shfl_down(s, off);

  __shared__ float red[4];
  const int wave = t >> 6;
  if ((t & 63) == 0) red[wave] = s;
  __syncthreads();
  float tot = red[0] + red[1] + red[2] + red[3];
  float scale = g[c] * rsqrtf(tot);
  w_all[(size_t)mat * CC * CIN + c * CIN + t] = f2h(val * scale);
}

// ---------------------------------------------------------------------------
// Kernel 2: projection GEMM.  1D grid 768, XCD-swizzled (4 c-tiles sharing an
// X-tile land on one XCD's L2).  Register-staged double-buffered LDS,
// 1 barrier per ktile, loads issued 2 ktiles ahead.
//  mz 0,1 (Q,K): out[b,h,s,d];  mz 2 (V): out[b,h,d,s] via swapped operands.
// X staged with scalar f2h + b16 writes (round-2 layout: ~0 conflicts).
// ---------------------------------------------------------------------------
__global__ __launch_bounds__(256)
void proj_kernel(const float* __restrict__ query, const float* __restrict__ key,
                 const ushort* __restrict__ w_all,
                 const float* __restrict__ bq, const float* __restrict__ bk,
                 const float* __restrict__ bv,
                 ushort* __restrict__ qkv) {
  const int wg  = blockIdx.x;                       // 0..767
  const int swb = (wg & 7) * 96 + (wg >> 3);        // bijective XCD swizzle
  const int tn = swb & 3, tm = (swb >> 2) & 7;
  const int b  = (swb >> 5) & 7, mz = swb >> 8;
  const int t  = threadIdx.x;
  const int s0 = tm * 128, c0 = tn * 128;

  const float*  X    = (mz == 0) ? query : key;
  const ushort* wmat = w_all + (size_t)mz * CC * CIN;
  const float*  bias = (mz == 0) ? bq : (mz == 1) ? bk : bv;
  ushort*       outp = qkv + (size_t)mz * NB * NH * SS * DH;
  const float*  Xb   = X + (size_t)b * CIN * SS;
  const uint*   wu   = (const uint*)wmat;

  __shared__ __align__(16) ushort Xs[2][128 * 40];   // [s_local][k_local] f16
  __shared__ __align__(16) ushort Ws[2][128 * 40];   // [c_local][k_local] f16

  const int wave = t >> 6, lane = t & 63;
  const int wm = wave >> 1, wn = wave & 1;
  const int lrow = lane & 15, kg = lane >> 4;

  // staging geometry
  const int row = t >> 5;   // 0..7  (k sub-row for X)
  const int f4  = t & 31;   // s quad
  const int iu  = t & 15;   // k-uint for W
  const int cb  = t >> 4;   // c sub-row for W

  float4 xr[4];
  uint   wr[8];
  auto LOADT = [&](int kt) {
    const int k0 = kt * 32;
    #pragma unroll
    for (int p = 0; p < 4; p++)
      xr[p] = *(const float4*)&Xb[(size_t)(k0 + row + p * 8) * SS + s0 + f4 * 4];
    #pragma unroll
    for (int p = 0; p < 8; p++)
      wr[p] = wu[(size_t)(c0 + cb + p * 16) * (CIN / 2) + (k0 >> 1) + iu];
  };
  auto STORET = [&](int buf) {
    #pragma unroll
    for (int p = 0; p < 4; p++) {
      const int kr = row + p * 8;
      Xs[buf][(f4 * 4 + 0) * 40 + kr] = f2h(xr[p].x);
      Xs[buf][(f4 * 4 + 1) * 40 + kr] = f2h(xr[p].y);
      Xs[buf][(f4 * 4 + 2) * 40 + kr] = f2h(xr[p].z);
      Xs[buf][(f4 * 4 + 3) * 40 + kr] = f2h(xr[p].w);
    }
    #pragma unroll
    for (int p = 0; p < 8; p++)
      *(uint*)&Ws[buf][(cb + p * 16) * 40 + iu * 2] = wr[p];
  };

  f32x4 acc[4][4];
  #pragma unroll
  for (int i = 0; i < 4; i++)
    #pragma unroll
    for (int j = 0; j < 4; j++) acc[i][j] = (f32x4){0.f, 0.f, 0.f, 0.f};

  LOADT(0);
  STORET(0);
  LOADT(1);
  __syncthreads();

  for (int kt = 0; kt < 8; ++kt) {
    const int cur = kt & 1;
    f16x8 a[4], bfr[4];
    #pragma unroll
    for (int i = 0; i < 4; i++)
      a[i] = *(const f16x8*)&Xs[cur][(wm * 64 + i * 16 + lrow) * 40 + kg * 8];
    #pragma unroll
    for (int j = 0; j < 4; j++)
      bfr[j] = *(const f16x8*)&Ws[cur][(wn * 64 + j * 16 + lrow) * 40 + kg * 8];
    if (mz == 2) {
      #pragma unroll
      for (int i = 0; i < 4; i++)
        #pragma unroll
        for (int j = 0; j < 4; j++)
          acc[i][j] = __builtin_amdgcn_mfma_f32_16x16x32_f16(bfr[j], a[i], acc[i][j], 0, 0, 0);
    } else {
      #pragma unroll
      for (int i = 0; i < 4; i++)
        #pragma unroll
        for (int j = 0; j < 4; j++)
          acc[i][j] = __builtin_amdgcn_mfma_f32_16x16x32_f16(a[i], bfr[j], acc[i][j], 0, 0, 0);
    }
    if (kt + 1 < 8) {
      STORET(cur ^ 1);             // regs for ktile kt+1 already in flight
      if (kt + 2 < 8) LOADT(kt + 2);
      __syncthreads();             // single barrier per ktile
    }
  }

  if (mz == 2) {
    #pragma unroll
    for (int i = 0; i < 4; i++) {
      const int sg = s0 + wm * 64 + i * 16 + lrow;
      #pragma unroll
      for (int j = 0; j < 4; j++) {
        #pragma unroll
        for (int r = 0; r < 4; r++) {
          const int c = c0 + wn * 64 + j * 16 + kg * 4 + r;
          outp[(((size_t)b * NH + (c >> 6)) * DH + (c & 63)) * SS + sg] =
              f2h(acc[i][j][r] + bias[c]);
        }
      }
    }
  } else {
    #pragma unroll
    for (int i = 0; i < 4; i++) {
      const int srow = s0 + wm * 64 + i * 16 + kg * 4;
      #pragma unroll
      for (int j = 0; j < 4; j++) {
        const int cgl = c0 + wn * 64 + j * 16 + lrow;
        const float bias_c = bias[cgl];
        const size_t obase = (((size_t)b * NH + (cgl >> 6)) * SS) * DH + (cgl & 63);
        #pragma unroll
        for (int r = 0; r < 4; r++)
          outp[obase + (size_t)(srow + r) * DH] = f2h(acc[i][j][r] + bias_c);
      }
    }
  }
}

// ---------------------------------------------------------------------------
// Kernel 3: causal flash attention. 1024 blocks (one 64-row q-tile each),
// XCD-swizzled (8 bh per XCD -> KV fits its L2).  Swapped-operand dataflow,
// 1 barrier per KV tile, defer-max online softmax (THR = 8 nats).
// ---------------------------------------------------------------------------
#define SCL 0.18033688f   // 0.125 * log2(e)
#define THR 11.5409f      // 8 nats in log2 units

__global__ __launch_bounds__(256, 3)
void attn_kernel(const ushort* __restrict__ Q, const ushort* __restrict__ K,
                 const ushort* __restrict__ V, float* __restrict__ out) {
  const int wg  = blockIdx.x;                  // 0..1023
  const int swb = (wg & 7) * 128 + (wg >> 3);  // bijective XCD swizzle
  const int qt = swb & 15;                     // q tile 0..15
  const int bh = swb >> 4;                     // 0..63
  const int nt = qt + 1;
  const int t = threadIdx.x;
  const int wave = t >> 6, lane = t & 63;
  const int lrow = lane & 15, kg = lane >> 4;

  __shared__ __align__(16) ushort Ks[2][64 * 64];
  __shared__ __align__(16) ushort Vs[2][64 * 64];
  __shared__ __align__(16) ushort Ps[64 * 64];

  const ushort* Qb = Q + (size_t)bh * SS * DH;
  const ushort* Kb = K + (size_t)bh * SS * DH;
  const ushort* Vb = V + (size_t)bh * DH * SS;   // [d][s]

  const int qg = qt * 64 + wave * 16 + lrow;

  f16x8 qa0 = *(const f16x8*)&Qb[(size_t)qg * DH + kg * 8];
  f16x8 qa1 = *(const f16x8*)&Qb[(size_t)qg * DH + 32 + kg * 8];

  float m = -1e30f, l = 0.f;
  f32x4 o[4];
  #pragma unroll
  for (int d = 0; d < 4; d++) o[d] = (f32x4){0.f, 0.f, 0.f, 0.f};

  // staging: 2 x 16B segments per thread per matrix
  const int r0 = t >> 3,        c0s = (t & 7) * 8;
  const int r1 = 32 + (t >> 3), c1s = c0s;
  const int ke0 = r0 * 64 + (c0s ^ (8 * (r0 & 7)));
  const int ke1 = r1 * 64 + (c1s ^ (8 * (r1 & 7)));

  f16x8 kr0, kr1, vr0, vr1;
  auto LOADT = [&](int jt) {
    const int j0 = jt * 64;
    kr0 = *(const f16x8*)&Kb[(size_t)(j0 + r0) * DH + c0s];
    kr1 = *(const f16x8*)&Kb[(size_t)(j0 + r1) * DH + c1s];
    vr0 = *(const f16x8*)&Vb[(size_t)r0 * SS + j0 + c0s];
    vr1 = *(const f16x8*)&Vb[(size_t)r1 * SS + j0 + c1s];
  };
  auto STORET = [&](int buf) {
    *(f16x8*)&Ks[buf][ke0] = kr0;
    *(f16x8*)&Ks[buf][ke1] = kr1;
    *(f16x8*)&Vs[buf][ke0] = vr0;
    *(f16x8*)&Vs[buf][ke1] = vr1;
  };

  LOADT(0);
  STORET(0);
  if (nt > 1) LOADT(1);
  __syncthreads();

  const int psrow = (wave * 16 + lrow) * 64;
  const int swz = 8 * (lrow & 7);

  for (int jt = 0; jt < nt; ++jt) {
    const int cur = jt & 1;
    const ushort* Kc = Ks[cur];
    const ushort* Vc = Vs[cur];
    const int j0 = jt * 64;
    const bool diag = (jt == qt);

    // S^T = K·Q^T for this wave's 16 q-rows x 64 keys
    f32x4 z[4];
    #pragma unroll
    for (int cf = 0; cf < 4; cf++) z[cf] = (f32x4){0.f, 0.f, 0.f, 0.f};
    #pragma unroll
    for (int cf = 0; cf < 4; ++cf) {
      const int krow = (cf * 16 + lrow) * 64;
      f16x8 ka0 = *(const f16x8*)&Kc[krow + ((kg * 8) ^ swz)];
      f16x8 ka1 = *(const f16x8*)&Kc[krow + ((32 + kg * 8) ^ swz)];
      z[cf] = __builtin_amdgcn_mfma_f32_16x16x32_f16(ka0, qa0, z[cf], 0, 0, 0);
      z[cf] = __builtin_amdgcn_mfma_f32_16x16x32_f16(ka1, qa1, z[cf], 0, 0, 0);
    }

    // online softmax with defer-max
    float x[16];
    #pragma unroll
    for (int cf = 0; cf < 4; cf++)
      #pragma unroll
      for (int r = 0; r < 4; r++) {
        float v = z[cf][r] * SCL;
        if (diag) {
          const int keyi = j0 + cf * 16 + kg * 4 + r;
          if (keyi >= qg) v = -3e8f;
        }
        x[cf * 4 + r] = v;
      }
    float mx = x[0];
    #pragma unroll
    for (int i = 1; i < 16; i++) mx = fmaxf(mx, x[i]);
    mx = fmaxf(mx, __shfl_xor(mx, 16));
    mx = fmaxf(mx, __shfl_xor(mx, 32));
    if (__any(mx > m + THR)) {
      const float mn = fmaxf(m, mx);
      const float corr = exp2f(m - mn);
      m = mn;
      l *= corr;
      #pragma unroll
      for (int d = 0; d < 4; d++) o[d] *= corr;
    }
    float ps = 0.f;
    #pragma unroll
    for (int i = 0; i < 16; i++) { x[i] = exp2f(x[i] - m); ps += x[i]; }
    ps += __shfl_xor(ps, 16);
    ps += __shfl_xor(ps, 32);
    l += ps;

    // P -> f16, swizzled LDS, read back as B-fragments
    #pragma unroll
    for (int cf = 0; cf < 4; cf++) {
      h16x2 p01 = __builtin_amdgcn_cvt_pkrtz(x[cf * 4 + 0], x[cf * 4 + 1]);
      h16x2 p23 = __builtin_amdgcn_cvt_pkrtz(x[cf * 4 + 2], x[cf * 4 + 3]);
      const int k0 = cf * 16 + kg * 4;
      *(h16x2*)&Ps[psrow + (k0 ^ swz)] = p01;
      *(h16x2*)&Ps[psrow + ((k0 + 2) ^ swz)] = p23;
    }
    f16x8 pa0 = *(const f16x8*)&Ps[psrow + ((kg * 8) ^ swz)];
    f16x8 pa1 = *(const f16x8*)&Ps[psrow + ((32 + kg * 8) ^ swz)];

    // O^T += V^T · P^T
    #pragma unroll
    for (int dt = 0; dt < 4; ++dt) {
      const int vrow = (dt * 16 + lrow) * 64;
      f16x8 va0 = *(const f16x8*)&Vc[vrow + ((kg * 8) ^ swz)];
      f16x8 va1 = *(const f16x8*)&Vc[vrow + ((32 + kg * 8) ^ swz)];
      o[dt] = __builtin_amdgcn_mfma_f32_16x16x32_f16(va0, pa0, o[dt], 0, 0, 0);
      o[dt] = __builtin_amdgcn_mfma_f32_16x16x32_f16(va1, pa1, o[dt], 0, 0, 0);
    }

    if (jt + 1 < nt) {
      STORET(cur ^ 1);               // regs for tile jt+1 already in flight
      if (jt + 2 < nt) LOADT(jt + 2);
      __syncthreads();               // single barrier per tile
    }
  }

  // epilogue: O^T is already [c][q] — direct coalesced stores
  const int b = bh >> 3, h = bh & 7;
  float* ob = out + ((size_t)b * CC + h * DH) * SS;
  float inv = (l > 0.f) ? 1.f / l : 0.f;
  if (qg == 0) inv = 0.f;            // start_mask: row 0 has no valid keys
  #pragma unroll
  for (int dt = 0; dt < 4; dt++)
    #pragma unroll
    for (int r = 0; r < 4; r++)
      ob[(size_t)(dt * 16 + kg * 4 + r) * SS + qg] = o[dt][r] * inv;
}

// ---------------------------------------------------------------------------
extern "C" void kernel_launch(void* const* d_in, const int* in_sizes, int n_in,
                              void* d_out, int out_size, void* d_ws, size_t ws_size,
                              hipStream_t stream) {
  const float* query = (const float*)d_in[0];
  const float* key   = (const float*)d_in[1];
  const float* vq = (const float*)d_in[2];
  const float* gq = (const float*)d_in[3];
  const float* bq = (const float*)d_in[4];
  const float* vk = (const float*)d_in[5];
  const float* gk = (const float*)d_in[6];
  const float* bk = (const float*)d_in[7];
  const float* vv = (const float*)d_in[8];
  const float* gv = (const float*)d_in[9];
  const float* bv = (const float*)d_in[10];
  float* out = (float*)d_out;

  ushort* w_all = (ushort*)d_ws;                              // [3][512][256] f16
  ushort* qkv   = (ushort*)((char*)d_ws + (size_t)3 * CC * CIN * 2);
  ushort* qb  = qkv;
  ushort* kb2 = qkv + (size_t)NB * NH * SS * DH;
  ushort* vb2 = kb2 + (size_t)NB * NH * SS * DH;              // [b][h][d][s]

  wnorm_kernel<<<dim3(CC, 3), 256, 0, stream>>>(vq, gq, vk, gk, vv, gv, w_all);
  proj_kernel<<<768, 256, 0, stream>>>(query, key, w_all, bq, bk, bv, qkv);
  attn_kernel<<<1024, 256, 0, stream>>>(qb, kb2, vb2, out);
}

// Round 6
// 67.076 us; speedup vs baseline: 1.2854x; 1.2854x over previous
//
#include <hip/hip_runtime.h>

typedef _Float16 f16x8 __attribute__((ext_vector_type(8)));
typedef __fp16   h16x2 __attribute__((ext_vector_type(2)));
typedef float    f32x4 __attribute__((ext_vector_type(4)));
typedef uint     u32x4 __attribute__((ext_vector_type(4)));

#define NB   8
#define CIN  256
#define CC   512
#define SS   1024
#define NH   8
#define DH   64

static __device__ __forceinline__ ushort f2h(float f) {
  union { _Float16 h; ushort u; } cv;
  cv.h = (_Float16)f;
  return cv.u;
}
static __device__ __forceinline__ uint pk2u(float a, float b) {
  union { h16x2 h; uint u; } cv;
  cv.h = __builtin_amdgcn_cvt_pkrtz(a, b);
  return cv.u;
}

// ---------------------------------------------------------------------------
// Kernel 1: weight-norm  w[c,i] = g[c] * v[c,i] / ||v[c,:]||   -> f16
// ---------------------------------------------------------------------------
__global__ __launch_bounds__(256)
void wnorm_kernel(const float* __restrict__ vq, const float* __restrict__ gq,
                  const float* __restrict__ vk, const float* __restrict__ gk,
                  const float* __restrict__ vv, const float* __restrict__ gv,
                  ushort* __restrict__ w_all) {
  const int c   = blockIdx.x;
  const int mat = blockIdx.y;
  const int t   = threadIdx.x;
  const float* v = (mat == 0) ? vq : (mat == 1) ? vk : vv;
  const float* g = (mat == 0) ? gq : (mat == 1) ? gk : gv;

  float val = v[c * CIN + t];
  float s = val * val;
  #pragma unroll
  for (int off = 32; off; off >>= 1) s += __shfl_down(s, off);

  __shared__ float red[4];
  const int wave = t >> 6;
  if ((t & 63) == 0) red[wave] = s;
  __syncthreads();
  float tot = red[0] + red[1] + red[2] + red[3];
  float scale = g[c] * rsqrtf(tot);
  w_all[(size_t)mat * CC * CIN + c * CIN + t] = f2h(val * scale);
}

// ---------------------------------------------------------------------------
// Kernel 1b: transpose X f32 [b][k][s] -> Xt f16 [mat][b][s][k].
// 64x64 tiles via word-XOR-swizzled f32 LDS (2 lanes/bank both phases).
// grid 1024: kt = bx&3, st = (bx>>2)&15, b = (bx>>6)&7, mat = bx>>9.
// ---------------------------------------------------------------------------
__global__ __launch_bounds__(256)
void xpose_kernel(const float* __restrict__ query, const float* __restrict__ key,
                  ushort* __restrict__ Xt) {
  const int bx = blockIdx.x;
  const int kt = bx & 3, st = (bx >> 2) & 15, b = (bx >> 6) & 7, mat = bx >> 9;
  const float* Xf = ((mat == 0) ? query : key)
                    + (size_t)b * CIN * SS + (size_t)(kt * 64) * SS + st * 64;
  ushort* Ot = Xt + ((size_t)(mat * NB + b) * SS + st * 64) * CIN + kt * 64;

  __shared__ float T[64 * 64];
  const int t = threadIdx.x;

  // load phase: thread reads float4 (4 s) at one k; XOR word swizzle on write
  const int kl0 = t >> 4;          // 0..15
  const int s4  = (t & 15) * 4;
  #pragma unroll
  for (int p = 0; p < 4; p++) {
    const int kl = p * 16 + kl0;
    const float4 xv = *(const float4*)&Xf[(size_t)kl * SS + s4];
    T[(s4 + 0) * 64 + (kl ^ (s4 + 0))] = xv.x;
    T[(s4 + 1) * 64 + (kl ^ (s4 + 1))] = xv.y;
    T[(s4 + 2) * 64 + (kl ^ (s4 + 2))] = xv.z;
    T[(s4 + 3) * 64 + (kl ^ (s4 + 3))] = xv.w;
  }
  __syncthreads();

  // store phase: thread owns 16 k at one s; pack f16 pairs, 2x16B stores
  const int sl = t >> 2;           // 0..63
  const int k0 = (t & 3) * 16;
  uint ow[8];
  #pragma unroll
  for (int q = 0; q < 8; q++) {
    const float f0 = T[sl * 64 + ((k0 + 2 * q) ^ sl)];
    const float f1 = T[sl * 64 + ((k0 + 2 * q + 1) ^ sl)];
    ow[q] = pk2u(f0, f1);
  }
  *(u32x4*)&Ot[(size_t)sl * CIN + k0]     = (u32x4){ow[0], ow[1], ow[2], ow[3]};
  *(u32x4*)&Ot[(size_t)sl * CIN + k0 + 8] = (u32x4){ow[4], ow[5], ow[6], ow[7]};
}

// ---------------------------------------------------------------------------
// Kernel 2: projection GEMM, both operands k-contiguous f16.
// 1D grid 768, XCD-swizzled.  BK=64, attn-style XOR-swizzled 64-f16 rows,
// reg-prefetch 2 ktiles ahead, 2 barriers/ktile, single LDS buffer (32KB).
//  mz 0,1 (Q,K): out[b,h,s,d];  mz 2 (V): out[b,h,d,s] via swapped operands.
// ---------------------------------------------------------------------------
__global__ __launch_bounds__(256)
void proj_kernel(const ushort* __restrict__ Xt, const ushort* __restrict__ w_all,
                 const float* __restrict__ bq, const float* __restrict__ bk,
                 const float* __restrict__ bv,
                 ushort* __restrict__ qkv) {
  const int wg  = blockIdx.x;                       // 0..767
  const int swb = (wg & 7) * 96 + (wg >> 3);        // bijective XCD swizzle
  const int tn = swb & 3, tm = (swb >> 2) & 7;
  const int b  = (swb >> 5) & 7, mz = swb >> 8;
  const int t  = threadIdx.x;
  const int s0 = tm * 128, c0 = tn * 128;

  const ushort* Xb = Xt + ((size_t)(((mz == 0) ? 0 : NB) + b) * SS + s0) * CIN;
  const ushort* Wb = w_all + (size_t)mz * CC * CIN + (size_t)c0 * CIN;
  const float*  bias = (mz == 0) ? bq : (mz == 1) ? bk : bv;
  ushort*       outp = qkv + (size_t)mz * NB * NH * SS * DH;

  __shared__ __align__(16) ushort Xs[128 * 64];
  __shared__ __align__(16) ushort Ws[128 * 64];

  const int wave = t >> 6, lane = t & 63;
  const int wm = wave >> 1, wn = wave & 1;
  const int lrow = lane & 15, kg = lane >> 4;

  const int srow = t >> 3;         // 0..31 staging row within 32-row group
  const int scol = (t & 7) * 8;    // f16 col (16B seg)

  f16x8 xr[4], wr[4];
  auto LOADT = [&](int kt) {
    const int k0 = kt * 64;
    #pragma unroll
    for (int q = 0; q < 4; q++) {
      const int row = q * 32 + srow;
      xr[q] = *(const f16x8*)&Xb[(size_t)row * CIN + k0 + scol];
      wr[q] = *(const f16x8*)&Wb[(size_t)row * CIN + k0 + scol];
    }
  };
  auto STORET = [&]() {
    #pragma unroll
    for (int q = 0; q < 4; q++) {
      const int row = q * 32 + srow;
      const int off = row * 64 + (scol ^ (8 * (row & 7)));
      *(f16x8*)&Xs[off] = xr[q];
      *(f16x8*)&Ws[off] = wr[q];
    }
  };

  f32x4 acc[4][4];
  #pragma unroll
  for (int i = 0; i < 4; i++)
    #pragma unroll
    for (int j = 0; j < 4; j++) acc[i][j] = (f32x4){0.f, 0.f, 0.f, 0.f};

  LOADT(0);
  STORET();
  LOADT(1);
  __syncthreads();

  const int swzA = 8 * (lrow & 7);
  for (int kt = 0; kt < 4; ++kt) {
    f16x8 a[4][2], bf[4][2];
    #pragma unroll
    for (int i = 0; i < 4; i++) {
      const int ra = (wm * 64 + i * 16 + lrow) * 64;
      a[i][0] = *(const f16x8*)&Xs[ra + ((kg * 8) ^ swzA)];
      a[i][1] = *(const f16x8*)&Xs[ra + ((32 + kg * 8) ^ swzA)];
      const int rb = (wn * 64 + i * 16 + lrow) * 64;
      bf[i][0] = *(const f16x8*)&Ws[rb + ((kg * 8) ^ swzA)];
      bf[i][1] = *(const f16x8*)&Ws[rb + ((32 + kg * 8) ^ swzA)];
    }
    if (mz == 2) {
      #pragma unroll
      for (int i = 0; i < 4; i++)
        #pragma unroll
        for (int j = 0; j < 4; j++) {
          acc[i][j] = __builtin_amdgcn_mfma_f32_16x16x32_f16(bf[j][0], a[i][0], acc[i][j], 0, 0, 0);
          acc[i][j] = __builtin_amdgcn_mfma_f32_16x16x32_f16(bf[j][1], a[i][1], acc[i][j], 0, 0, 0);
        }
    } else {
      #pragma unroll
      for (int i = 0; i < 4; i++)
        #pragma unroll
        for (int j = 0; j < 4; j++) {
          acc[i][j] = __builtin_amdgcn_mfma_f32_16x16x32_f16(a[i][0], bf[j][0], acc[i][j], 0, 0, 0);
          acc[i][j] = __builtin_amdgcn_mfma_f32_16x16x32_f16(a[i][1], bf[j][1], acc[i][j], 0, 0, 0);
        }
    }
    if (kt < 3) {
      __syncthreads();           // all waves done reading this ktile
      STORET();                  // write ktile kt+1 (regs already loaded)
      if (kt < 2) LOADT(kt + 2);
      __syncthreads();           // ktile kt+1 visible
    }
  }

  if (mz == 2) {
    #pragma unroll
    for (int i = 0; i < 4; i++) {
      const int sg = s0 + wm * 64 + i * 16 + lrow;
      #pragma unroll
      for (int j = 0; j < 4; j++) {
        #pragma unroll
        for (int r = 0; r < 4; r++) {
          const int c = c0 + wn * 64 + j * 16 + kg * 4 + r;
          outp[(((size_t)b * NH + (c >> 6)) * DH + (c & 63)) * SS + sg] =
              f2h(acc[i][j][r] + bias[c]);
        }
      }
    }
  } else {
    #pragma unroll
    for (int i = 0; i < 4; i++) {
      const int srw = s0 + wm * 64 + i * 16 + kg * 4;
      #pragma unroll
      for (int j = 0; j < 4; j++) {
        const int cgl = c0 + wn * 64 + j * 16 + lrow;
        const float bias_c = bias[cgl];
        const size_t obase = (((size_t)b * NH + (cgl >> 6)) * SS) * DH + (cgl & 63);
        #pragma unroll
        for (int r = 0; r < 4; r++)
          outp[obase + (size_t)(srw + r) * DH] = f2h(acc[i][j][r] + bias_c);
      }
    }
  }
}

// ---------------------------------------------------------------------------
// Kernel 3: causal flash attention. 1024 blocks (one 64-row q-tile each),
// XCD-swizzled.  Swapped-operand dataflow, 1 barrier per KV tile,
// defer-max online softmax.
// ---------------------------------------------------------------------------
#define SCL 0.18033688f   // 0.125 * log2(e)
#define THR 11.5409f      // 8 nats in log2 units

__global__ __launch_bounds__(256, 3)
void attn_kernel(const ushort* __restrict__ Q, const ushort* __restrict__ K,
                 const ushort* __restrict__ V, float* __restrict__ out) {
  const int wg  = blockIdx.x;                  // 0..1023
  const int swb = (wg & 7) * 128 + (wg >> 3);  // bijective XCD swizzle
  const int qt = swb & 15;                     // q tile 0..15
  const int bh = swb >> 4;                     // 0..63
  const int nt = qt + 1;
  const int t = threadIdx.x;
  const int wave = t >> 6, lane = t & 63;
  const int lrow = lane & 15, kg = lane >> 4;

  __shared__ __align__(16) ushort Ks[2][64 * 64];
  __shared__ __align__(16) ushort Vs[2][64 * 64];
  __shared__ __align__(16) ushort Ps[64 * 64];

  const ushort* Qb = Q + (size_t)bh * SS * DH;
  const ushort* Kb = K + (size_t)bh * SS * DH;
  const ushort* Vb = V + (size_t)bh * DH * SS;   // [d][s]

  const int qg = qt * 64 + wave * 16 + lrow;

  f16x8 qa0 = *(const f16x8*)&Qb[(size_t)qg * DH + kg * 8];
  f16x8 qa1 = *(const f16x8*)&Qb[(size_t)qg * DH + 32 + kg * 8];

  float m = -1e30f, l = 0.f;
  f32x4 o[4];
  #pragma unroll
  for (int d = 0; d < 4; d++) o[d] = (f32x4){0.f, 0.f, 0.f, 0.f};

  const int r0 = t >> 3,        c0s = (t & 7) * 8;
  const int r1 = 32 + (t >> 3), c1s = c0s;
  const int ke0 = r0 * 64 + (c0s ^ (8 * (r0 & 7)));
  const int ke1 = r1 * 64 + (c1s ^ (8 * (r1 & 7)));

  f16x8 kr0, kr1, vr0, vr1;
  auto LOADT = [&](int jt) {
    const int j0 = jt * 64;
    kr0 = *(const f16x8*)&Kb[(size_t)(j0 + r0) * DH + c0s];
    kr1 = *(const f16x8*)&Kb[(size_t)(j0 + r1) * DH + c1s];
    vr0 = *(const f16x8*)&Vb[(size_t)r0 * SS + j0 + c0s];
    vr1 = *(const f16x8*)&Vb[(size_t)r1 * SS + j0 + c1s];
  };
  auto STORET = [&](int buf) {
    *(f16x8*)&Ks[buf][ke0] = kr0;
    *(f16x8*)&Ks[buf][ke1] = kr1;
    *(f16x8*)&Vs[buf][ke0] = vr0;
    *(f16x8*)&Vs[buf][ke1] = vr1;
  };

  LOADT(0);
  STORET(0);
  if (nt > 1) LOADT(1);
  __syncthreads();

  const int psrow = (wave * 16 + lrow) * 64;
  const int swz = 8 * (lrow & 7);

  for (int jt = 0; jt < nt; ++jt) {
    const int cur = jt & 1;
    const ushort* Kc = Ks[cur];
    const ushort* Vc = Vs[cur];
    const int j0 = jt * 64;
    const bool diag = (jt == qt);

    f32x4 z[4];
    #pragma unroll
    for (int cf = 0; cf < 4; cf++) z[cf] = (f32x4){0.f, 0.f, 0.f, 0.f};
    #pragma unroll
    for (int cf = 0; cf < 4; ++cf) {
      const int krow = (cf * 16 + lrow) * 64;
      f16x8 ka0 = *(const f16x8*)&Kc[krow + ((kg * 8) ^ swz)];
      f16x8 ka1 = *(const f16x8*)&Kc[krow + ((32 + kg * 8) ^ swz)];
      z[cf] = __builtin_amdgcn_mfma_f32_16x16x32_f16(ka0, qa0, z[cf], 0, 0, 0);
      z[cf] = __builtin_amdgcn_mfma_f32_16x16x32_f16(ka1, qa1, z[cf], 0, 0, 0);
    }

    float x[16];
    #pragma unroll
    for (int cf = 0; cf < 4; cf++)
      #pragma unroll
      for (int r = 0; r < 4; r++) {
        float v = z[cf][r] * SCL;
        if (diag) {
          const int keyi = j0 + cf * 16 + kg * 4 + r;
          if (keyi >= qg) v = -3e8f;
        }
        x[cf * 4 + r] = v;
      }
    float mx = x[0];
    #pragma unroll
    for (int i = 1; i < 16; i++) mx = fmaxf(mx, x[i]);
    mx = fmaxf(mx, __shfl_xor(mx, 16));
    mx = fmaxf(mx, __shfl_xor(mx, 32));
    if (__any(mx > m + THR)) {
      const float mn = fmaxf(m, mx);
      const float corr = exp2f(m - mn);
      m = mn;
      l *= corr;
      #pragma unroll
      for (int d = 0; d < 4; d++) o[d] *= corr;
    }
    float ps = 0.f;
    #pragma unroll
    for (int i = 0; i < 16; i++) { x[i] = exp2f(x[i] - m); ps += x[i]; }
    ps += __shfl_xor(ps, 16);
    ps += __shfl_xor(ps, 32);
    l += ps;

    #pragma unroll
    for (int cf = 0; cf < 4; cf++) {
      h16x2 p01 = __builtin_amdgcn_cvt_pkrtz(x[cf * 4 + 0], x[cf * 4 + 1]);
      h16x2 p23 = __builtin_amdgcn_cvt_pkrtz(x[cf * 4 + 2], x[cf * 4 + 3]);
      const int k0 = cf * 16 + kg * 4;
      *(h16x2*)&Ps[psrow + (k0 ^ swz)] = p01;
      *(h16x2*)&Ps[psrow + ((k0 + 2) ^ swz)] = p23;
    }
    f16x8 pa0 = *(const f16x8*)&Ps[psrow + ((kg * 8) ^ swz)];
    f16x8 pa1 = *(const f16x8*)&Ps[psrow + ((32 + kg * 8) ^ swz)];

    #pragma unroll
    for (int dt = 0; dt < 4; ++dt) {
      const int vrow = (dt * 16 + lrow) * 64;
      f16x8 va0 = *(const f16x8*)&Vc[vrow + ((kg * 8) ^ swz)];
      f16x8 va1 = *(const f16x8*)&Vc[vrow + ((32 + kg * 8) ^ swz)];
      o[dt] = __builtin_amdgcn_mfma_f32_16x16x32_f16(va0, pa0, o[dt], 0, 0, 0);
      o[dt] = __builtin_amdgcn_mfma_f32_16x16x32_f16(va1, pa1, o[dt], 0, 0, 0);
    }

    if (jt + 1 < nt) {
      STORET(cur ^ 1);
      if (jt + 2 < nt) LOADT(jt + 2);
      __syncthreads();
    }
  }

  const int b = bh >> 3, h = bh & 7;
  float* ob = out + ((size_t)b * CC + h * DH) * SS;
  float inv = (l > 0.f) ? 1.f / l : 0.f;
  if (qg == 0) inv = 0.f;
  #pragma unroll
  for (int dt = 0; dt < 4; dt++)
    #pragma unroll
    for (int r = 0; r < 4; r++)
      ob[(size_t)(dt * 16 + kg * 4 + r) * SS + qg] = o[dt][r] * inv;
}

// ---------------------------------------------------------------------------
extern "C" void kernel_launch(void* const* d_in, const int* in_sizes, int n_in,
                              void* d_out, int out_size, void* d_ws, size_t ws_size,
                              hipStream_t stream) {
  const float* query = (const float*)d_in[0];
  const float* key   = (const float*)d_in[1];
  const float* vq = (const float*)d_in[2];
  const float* gq = (const float*)d_in[3];
  const float* bq = (const float*)d_in[4];
  const float* vk = (const float*)d_in[5];
  const float* gk = (const float*)d_in[6];
  const float* bk = (const float*)d_in[7];
  const float* vv = (const float*)d_in[8];
  const float* gv = (const float*)d_in[9];
  const float* bv = (const float*)d_in[10];
  float* out = (float*)d_out;

  ushort* w_all = (ushort*)d_ws;                                   // [3][512][256] f16
  ushort* qkv   = w_all + (size_t)3 * CC * CIN;                    // [3][B][NH][..]
  ushort* Xt    = qkv + (size_t)3 * NB * NH * SS * DH;             // [2][B][S][K] f16
  ushort* qb  = qkv;
  ushort* kb2 = qkv + (size_t)NB * NH * SS * DH;
  ushort* vb2 = kb2 + (size_t)NB * NH * SS * DH;                   // [b][h][d][s]

  wnorm_kernel<<<dim3(CC, 3), 256, 0, stream>>>(vq, gq, vk, gk, vv, gv, w_all);
  xpose_kernel<<<1024, 256, 0, stream>>>(query, key, Xt);
  proj_kernel<<<768, 256, 0, stream>>>(Xt, w_all, bq, bk, bv, qkv);
  attn_kernel<<<1024, 256, 0, stream>>>(qb, kb2, vb2, out);
}